// Round 6
// baseline (724.079 us; speedup 1.0000x reference)
//
#include <hip/hip_runtime.h>

#define NN 256
#define TT 512
#define BB 1024
#define DTC 0.01f

typedef _Float16 half8 __attribute__((ext_vector_type(8)));
typedef float f32x4 __attribute__((ext_vector_type(4)));

// MFMA with A pinned in AGPRs (W resident for the whole kernel).
__device__ __forceinline__ f32x4 mfma_z(half8 a, half8 b) {
  f32x4 d;
  asm("v_mfma_f32_16x16x32_f16 %0, %1, %2, 0" : "=v"(d) : "a"(a), "v"(b));
  return d;
}
__device__ __forceinline__ void mfma_p(f32x4& c, half8 a, half8 b) {
  asm("v_mfma_f32_16x16x32_f16 %0, %1, %2, %0" : "+v"(c) : "a"(a), "v"(b));
}

// max with lane rotated-by-CTRL within the 16-lane DPP row (VALU pipe, no LDS)
template <int CTRL>
__device__ __forceinline__ float rormax(float x) {
  int yi = __builtin_amdgcn_update_dpp(0, __float_as_int(x), CTRL, 0xf, 0xf, false);
  return fmaxf(x, __int_as_float(yi));
}

// One block = 16 batch rows, 4 waves, wave w owns neurons [64w,64w+64).
// GEMM transposed: D[m=neuron][n=batchrow] = W_eff^T * s^T, 3-term f16 hi/lo.
// W^T in 256 AGPRs. K-loop pipelined in 4 groups of 2 k-steps; group g+1's
// LDS reads issue inside group g's MFMA region; sched_barrier(0) pins the
// group structure so register pressure stays low and the 12 accumulator
// chains can interleave at pipe rate instead of serializing at MFMA latency.
__global__ __launch_bounds__(256, 1) void ring_attractor_kernel(
    const float* __restrict__ W, const float* __restrict__ log_scale,
    const float* __restrict__ gain, const float* __restrict__ bias,
    const float* __restrict__ log_tau, const float* __restrict__ vscale_p,
    const float* __restrict__ lscale_p, const float* __restrict__ velocity,
    const float* __restrict__ landmarks, float* __restrict__ out) {
  __shared__ __align__(16) _Float16 fragH[2][4096];
  __shared__ __align__(16) _Float16 fragL[2][4096];
  __shared__ __align__(16) float maxslot[2][4];

  const int tid = threadIdx.x;
  const int w  = tid >> 6;   // 0..3
  const int l  = tid & 63;
  const int g  = l >> 4;
  const int li = l & 15;
  const int br = blockIdx.x * 16 + li;

  const float es  = expf(log_scale[0]);
  const float vs  = vscale_p[0];
  const float lms = lscale_p[0];

  float gain_r[4][4], bias_r[4][4], coef_r[4][4];
#pragma unroll
  for (int nt = 0; nt < 4; ++nt)
#pragma unroll
    for (int q = 0; q < 4; ++q) {
      int c = w * 64 + nt * 16 + g * 4 + q;
      gain_r[nt][q] = gain[c];
      bias_r[nt][q] = bias[c];
      coef_r[nt][q] = DTC / expf(log_tau[c]);
    }

  // Resident W_eff^T hi/lo. A[m][k]: m = w*64+nt*16+li, k = 32ks+4g+(j&3)+16(j>>2)
  half8 whi[4][8], wlo[4][8];
#pragma unroll
  for (int nt = 0; nt < 4; ++nt)
#pragma unroll
    for (int ks = 0; ks < 8; ++ks) {
      half8 hi, lo;
#pragma unroll
      for (int j = 0; j < 8; ++j) {
        int k = ks * 32 + g * 4 + (j & 3) + ((j >> 2) << 4);
        int m = w * 64 + nt * 16 + li;
        float wv = W[k * NN + m] * es;
        _Float16 h = (_Float16)wv;
        hi[j] = h;
        lo[j] = (_Float16)(wv - (float)h);
      }
      whi[nt][ks] = hi;
      wlo[nt][ks] = lo;
    }

  float s_r[4][4];
#pragma unroll
  for (int nt = 0; nt < 4; ++nt)
#pragma unroll
    for (int q = 0; q < 4; ++q) s_r[nt][q] = 0.f;

  // Each lane owns 2 frag slots per buffer (k-slices ks = 2w, 2w+1)
  const int wb0 = ((w * 2 + 0) * 64 + g * 16 + li) * 8;
  const int wb1 = ((w * 2 + 1) * 64 + g * 16 + li) * 8;
  {
    half8 z;
#pragma unroll
    for (int j = 0; j < 8; ++j) z[j] = (_Float16)0.f;
    *reinterpret_cast<half8*>(&fragH[0][wb0]) = z;
    *reinterpret_cast<half8*>(&fragH[0][wb1]) = z;
    *reinterpret_cast<half8*>(&fragL[0][wb0]) = z;
    *reinterpret_cast<half8*>(&fragL[0][wb1]) = z;
    if (tid < 8) maxslot[tid >> 2][tid & 3] = 0.f;
  }
  float inv_scale = 1.f;
  float amPrev = 0.f;
  __syncthreads();

// LDS frag read pair for k-slice KS of buffer CUR
#define RD(CUR, KS, BH, BL)                                                    \
  {                                                                            \
    const int rb = ((KS) * 64 + g * 16 + li) * 8;                              \
    BH = *reinterpret_cast<const half8*>(&fragH[CUR][rb]);                     \
    BL = *reinterpret_cast<const half8*>(&fragL[CUR][rb]);                     \
  }

// 12-chain MFMA block for k-slice KS (accumulate / zero-init variants)
#define K12(KS, BH, BL)                                                        \
  mfma_p(a0h, whi[0][KS], BH);                                                 \
  mfma_p(a1h, whi[1][KS], BH);                                                 \
  mfma_p(a2h, whi[2][KS], BH);                                                 \
  mfma_p(a3h, whi[3][KS], BH);                                                 \
  mfma_p(a0l, wlo[0][KS], BH);                                                 \
  mfma_p(a1l, wlo[1][KS], BH);                                                 \
  mfma_p(a2l, wlo[2][KS], BH);                                                 \
  mfma_p(a3l, wlo[3][KS], BH);                                                 \
  mfma_p(a0c, whi[0][KS], BL);                                                 \
  mfma_p(a1c, whi[1][KS], BL);                                                 \
  mfma_p(a2c, whi[2][KS], BL);                                                 \
  mfma_p(a3c, whi[3][KS], BL);
#define K12Z(KS, BH, BL)                                                       \
  a0h = mfma_z(whi[0][KS], BH);                                                \
  a1h = mfma_z(whi[1][KS], BH);                                                \
  a2h = mfma_z(whi[2][KS], BH);                                                \
  a3h = mfma_z(whi[3][KS], BH);                                                \
  a0l = mfma_z(wlo[0][KS], BH);                                                \
  a1l = mfma_z(wlo[1][KS], BH);                                                \
  a2l = mfma_z(wlo[2][KS], BH);                                                \
  a3l = mfma_z(wlo[3][KS], BH);                                                \
  a0c = mfma_z(whi[0][KS], BL);                                                \
  a1c = mfma_z(whi[1][KS], BL);                                                \
  a2c = mfma_z(whi[2][KS], BL);                                                \
  a3c = mfma_z(whi[3][KS], BL);

// Per-tile elementwise tail: consume accs of tile NT, update s_r[NT][*], am.
#define TAIL(NT, AH, AL, AC)                                                   \
  {                                                                            \
    f32x4 av = (AH + AL) + AC;                                                 \
    _Pragma("unroll")                                                          \
    for (int q = 0; q < 4; ++q) {                                              \
      float ext;                                                               \
      if (w == 0) {                                                            \
        f32x4 ev = (NT == 0) ? lm0 : (NT == 1) ? lm1 : (NT == 2) ? lm2 : lm3;  \
        ext = lms * ev[q];                                                     \
      } else if (w == 1) {                                                     \
        ext = vs * ((NT < 2) ? vv0 : vv1);                                     \
      } else {                                                                 \
        ext = 0.f;                                                             \
      }                                                                        \
      float tot = __builtin_fmaf(av[q], inv_scale, ext);                       \
      float rate = fmaxf(__builtin_fmaf(gain_r[NT][q], tot, bias_r[NT][q]),    \
                         0.f);                                                 \
      float sv = s_r[NT][q];                                                   \
      sv = __builtin_fmaf(coef_r[NT][q], rate - sv, sv);                       \
      s_r[NT][q] = sv;                                                         \
      am = fmaxf(am, fabsf(sv));                                               \
    }                                                                          \
  }

#define SB() __builtin_amdgcn_sched_barrier(0)

#define STEP(T, CUR)                                                           \
  {                                                                            \
    /* (1) reduce prev step's per-lane max -> maxslot[CUR] (off crit path) */  \
    {                                                                          \
      float r = amPrev;                                                        \
      r = rormax<0x121>(r);                                                    \
      r = rormax<0x122>(r);                                                    \
      r = rormax<0x124>(r);                                                    \
      r = rormax<0x128>(r);                                                    \
      r = fmaxf(r, __shfl_xor(r, 16));                                         \
      r = fmaxf(r, __shfl_xor(r, 32));                                         \
      if (l == 0) maxslot[CUR][w] = r;                                         \
    }                                                                          \
    /* (2) M_{T-1} -> scale for s_{T+1} (branch-free, target max 2^7) */       \
    float scale_n, inv_n;                                                      \
    {                                                                          \
      f32x4 mv = *reinterpret_cast<const f32x4*>(&maxslot[CUR ^ 1][0]);        \
      float M = fmaxf(fmaxf(mv[0], mv[1]), fmaxf(mv[2], mv[3]));               \
      int e = 134 - (int)(__float_as_uint(M) >> 23);                           \
      e = e > 9 ? 9 : e;                                                       \
      scale_n = __int_as_float((e + 127) << 23);                               \
      inv_n = __int_as_float((127 - e) << 23);                                 \
    }                                                                          \
    /* (3) ext inputs for this step; HBM latency hides under MFMA phase */     \
    f32x4 lm0{}, lm1{}, lm2{}, lm3{};                                          \
    float vv0 = 0.f, vv1 = 0.f;                                                \
    if (w == 0) {                                                              \
      const float* p = landmarks + ((size_t)(T)*BB + br) * 64 + g * 4;         \
      lm0 = *reinterpret_cast<const f32x4*>(p);                                \
      lm1 = *reinterpret_cast<const f32x4*>(p + 16);                           \
      lm2 = *reinterpret_cast<const f32x4*>(p + 32);                           \
      lm3 = *reinterpret_cast<const f32x4*>(p + 48);                           \
    } else if (w == 1) {                                                       \
      const float* p = velocity + ((size_t)(T)*BB + br) * 2;                   \
      vv0 = p[0];                                                              \
      vv1 = p[1];                                                              \
    }                                                                          \
    /* (4) pipelined K-groups: reads for g+1 inside group g's region */        \
    half8 bh0, bl0, bh1, bl1, bh2, bl2, bh3, bl3;                              \
    f32x4 a0h, a1h, a2h, a3h, a0l, a1l, a2l, a3l, a0c, a1c, a2c, a3c;          \
    RD(CUR, 0, bh0, bl0)                                                       \
    RD(CUR, 1, bh1, bl1)                                                       \
    SB();                                                                      \
    RD(CUR, 2, bh2, bl2)                                                       \
    RD(CUR, 3, bh3, bl3)                                                       \
    K12Z(0, bh0, bl0)                                                          \
    K12(1, bh1, bl1)                                                           \
    SB();                                                                      \
    RD(CUR, 4, bh0, bl0)                                                       \
    RD(CUR, 5, bh1, bl1)                                                       \
    K12(2, bh2, bl2)                                                           \
    K12(3, bh3, bl3)                                                           \
    SB();                                                                      \
    RD(CUR, 6, bh2, bl2)                                                       \
    RD(CUR, 7, bh3, bl3)                                                       \
    K12(4, bh0, bl0)                                                           \
    K12(5, bh1, bl1)                                                           \
    SB();                                                                      \
    /* (5) last group: ks=6 full, ks=7 interleaved with tails/quantize */      \
    float am = 0.f;                                                            \
    K12(6, bh2, bl2)                                                           \
    mfma_p(a0h, whi[0][7], bh3);                                               \
    mfma_p(a0l, wlo[0][7], bh3);                                               \
    mfma_p(a0c, whi[0][7], bl3);                                               \
    mfma_p(a1h, whi[1][7], bh3);                                               \
    mfma_p(a1l, wlo[1][7], bh3);                                               \
    mfma_p(a1c, whi[1][7], bl3);                                               \
    asm volatile("s_nop 7" : "+v"(a0h), "+v"(a0l), "+v"(a0c));                 \
    TAIL(0, a0h, a0l, a0c)                                                     \
    mfma_p(a2h, whi[2][7], bh3);                                               \
    mfma_p(a2l, wlo[2][7], bh3);                                               \
    mfma_p(a2c, whi[2][7], bl3);                                               \
    TAIL(1, a1h, a1l, a1c)                                                     \
    mfma_p(a3h, whi[3][7], bh3);                                               \
    mfma_p(a3l, wlo[3][7], bh3);                                               \
    mfma_p(a3c, whi[3][7], bl3);                                               \
    /* quantize tiles 0,1 -> slot wb0 (hides under a2/a3 MFMAs) */             \
    {                                                                          \
      half8 h0, l0;                                                            \
      _Pragma("unroll")                                                        \
      for (int j = 0; j < 8; ++j) {                                            \
        float sc0 = s_r[j >> 2][j & 3] * scale_n;                              \
        _Float16 q0 = (_Float16)sc0;                                           \
        h0[j] = q0;                                                            \
        l0[j] = (_Float16)(sc0 - (float)q0);                                   \
      }                                                                        \
      *reinterpret_cast<half8*>(&fragH[CUR ^ 1][wb0]) = h0;                    \
      *reinterpret_cast<half8*>(&fragL[CUR ^ 1][wb0]) = l0;                    \
    }                                                                          \
    TAIL(2, a2h, a2l, a2c)                                                     \
    asm volatile("s_nop 7" : "+v"(a3h), "+v"(a3l), "+v"(a3c));                 \
    TAIL(3, a3h, a3l, a3c)                                                     \
    /* quantize tiles 2,3 -> slot wb1 */                                       \
    {                                                                          \
      half8 h1, l1;                                                            \
      _Pragma("unroll")                                                        \
      for (int j = 0; j < 8; ++j) {                                            \
        float sc1 = s_r[2 + (j >> 2)][j & 3] * scale_n;                        \
        _Float16 q1 = (_Float16)sc1;                                           \
        h1[j] = q1;                                                            \
        l1[j] = (_Float16)(sc1 - (float)q1);                                   \
      }                                                                        \
      *reinterpret_cast<half8*>(&fragH[CUR ^ 1][wb1]) = h1;                    \
      *reinterpret_cast<half8*>(&fragL[CUR ^ 1][wb1]) = l1;                    \
    }                                                                          \
    amPrev = am;                                                               \
    inv_scale = inv_n;                                                         \
    __syncthreads();                                                           \
  }

#pragma unroll 1
  for (int t = 0; t < TT; t += 2) {
    STEP(t, 0)
    STEP(t + 1, 1)
  }
#undef STEP
#undef TAIL
#undef K12
#undef K12Z
#undef RD
#undef SB

  // Epilogue: epg output = neurons [0,64) -> wave 0
  if (w == 0) {
#pragma unroll
    for (int nt = 0; nt < 4; ++nt) {
      f32x4 o;
#pragma unroll
      for (int q = 0; q < 4; ++q) o[q] = s_r[nt][q];
      *reinterpret_cast<f32x4*>(out + (size_t)br * 64 + nt * 16 + g * 4) = o;
    }
  }
}

extern "C" void kernel_launch(void* const* d_in, const int* in_sizes, int n_in,
                              void* d_out, int out_size, void* d_ws, size_t ws_size,
                              hipStream_t stream) {
  const float* W         = (const float*)d_in[0];
  const float* log_scale = (const float*)d_in[1];
  const float* gain      = (const float*)d_in[2];
  const float* bias      = (const float*)d_in[3];
  const float* log_tau   = (const float*)d_in[4];
  const float* vscale    = (const float*)d_in[5];
  const float* lscale    = (const float*)d_in[6];
  const float* velocity  = (const float*)d_in[7];
  const float* landmarks = (const float*)d_in[8];
  float* out = (float*)d_out;

  ring_attractor_kernel<<<dim3(BB / 16), dim3(256), 0, stream>>>(
      W, log_scale, gain, bias, log_tau, vscale, lscale, velocity, landmarks, out);
}